// Round 2
// baseline (4425.290 us; speedup 1.0000x reference)
//
#include <hip/hip_runtime.h>
#include <cstdint>
#include <cstddef>

namespace {

constexpr int kS   = 1024;   // query length
constexpr int kB   = 4;      // batch
constexpr int kH   = 1024;   // hidden
constexpr int kMem = 1024;   // MEM_LEN
constexpr int kK   = 2048;   // S + MEM_LEN

// ---------------------------------------------------------------------------
// GEMM: C[M,1024] = A[M,1024] @ W^T + bias   (W is [1024,1024], row = out-feat)
// MODE 0: A rows are direct (A + r*1024)
// MODE 1: A rows are kv_in gather: r -> (b = r>>11, j = r&2047);
//         j <  1024 : token_embedding[b, j]
//         j >= 1024 : mems[0, b, j-1024]
// Tile: BM=128, BN=64, BK=16, 256 threads, 8x4 micro-tile.
// ---------------------------------------------------------------------------
template <int MODE>
__global__ __launch_bounds__(256) void gemm_bias_kernel(
    const float* __restrict__ A, const float* __restrict__ temb,
    const float* __restrict__ mems, const float* __restrict__ W,
    const float* __restrict__ bias, float* __restrict__ C) {
  __shared__ float As[16][132];  // [k][m], padded
  __shared__ float Bs[16][68];   // [k][n], padded
  const int t  = threadIdx.x;
  const int bm = blockIdx.x;
  const int bn = blockIdx.y;
  const int tm = t & 15, tn = t >> 4;
  const int lr = t >> 1, lk = (t & 1) * 8;   // A tile loader: row lr, k lk..lk+7
  const int wr = t >> 2, wk = (t & 3) * 4;   // W tile loader: row wr, k wk..wk+3

  const float* arow;
  {
    const int r = bm * 128 + lr;
    if (MODE == 0) {
      arow = A + (size_t)r * kH;
    } else {
      const int bb = r >> 11, jj = r & 2047;
      arow = (jj < kS) ? (temb + ((size_t)bb * kS + jj) * kH)
                       : (mems + ((size_t)bb * kK + (jj - kS)) * kH);
    }
  }
  const float* wrow = W + (size_t)(bn * 64 + wr) * kH;

  float c[8][4] = {};
  for (int k0 = 0; k0 < kH; k0 += 16) {
    const float4 a0 = *(const float4*)(arow + k0 + lk);
    const float4 a1 = *(const float4*)(arow + k0 + lk + 4);
    const float4 w0 = *(const float4*)(wrow + k0 + wk);
    __syncthreads();  // protect previous iteration's LDS reads
    As[lk + 0][lr] = a0.x; As[lk + 1][lr] = a0.y;
    As[lk + 2][lr] = a0.z; As[lk + 3][lr] = a0.w;
    As[lk + 4][lr] = a1.x; As[lk + 5][lr] = a1.y;
    As[lk + 6][lr] = a1.z; As[lk + 7][lr] = a1.w;
    Bs[wk + 0][wr] = w0.x; Bs[wk + 1][wr] = w0.y;
    Bs[wk + 2][wr] = w0.z; Bs[wk + 3][wr] = w0.w;
    __syncthreads();
#pragma unroll
    for (int k = 0; k < 16; ++k) {
      const float4 av0 = *(const float4*)&As[k][tm * 8];
      const float4 av1 = *(const float4*)&As[k][tm * 8 + 4];
      const float4 bv  = *(const float4*)&Bs[k][tn * 4];
      const float am[8] = {av0.x, av0.y, av0.z, av0.w, av1.x, av1.y, av1.z, av1.w};
      const float bb[4] = {bv.x, bv.y, bv.z, bv.w};
#pragma unroll
      for (int mi = 0; mi < 8; ++mi)
#pragma unroll
        for (int ni = 0; ni < 4; ++ni) c[mi][ni] += am[mi] * bb[ni];
    }
  }
  const float4 bi = *(const float4*)(bias + bn * 64 + tn * 4);
#pragma unroll
  for (int mi = 0; mi < 8; ++mi) {
    const float4 o = make_float4(c[mi][0] + bi.x, c[mi][1] + bi.y,
                                 c[mi][2] + bi.z, c[mi][3] + bi.w);
    *(float4*)(C + (size_t)(bm * 128 + tm * 8 + mi) * kH + bn * 64 + tn * 4) = o;
  }
}

// ---------------------------------------------------------------------------
// Fused attention.
//   scores[i,j,b,n] = ( (q[i,b,n]+u[n])·k[j,b,n] + (q[i,b,n]+v[n])·kr[j+S-1-i,n] )/8
//                     - big[i>>8, (j%32)*64 + b*16 + n]
//   attn = softmax over n (16 heads);  OP[i*4+b, n*64+d] = sum_j attn * V[j*4+b, n*64+d]
// Grid: 512 blocks = (b in 0..3) x (i-tile of 8). 256 threads = 4 waves, 2 i's/wave.
// Lane l owns float-granules f = 4*l + 256*e (e=0..3): head n_e=(l>>4)+4e, d=4*(l&15)..+3.
// kr rows come from a 16-slot LDS ring (rel-shift sliding window, 1 barrier/j).
// ---------------------------------------------------------------------------
__global__ __launch_bounds__(256) void attn_kernel(
    const float* __restrict__ Qm, const float* __restrict__ Km,
    const float* __restrict__ Vm, const float* __restrict__ Rm,
    const float* __restrict__ u_, const float* __restrict__ v_,
    const float* __restrict__ amask, float* __restrict__ OP) {
  __shared__ float ring[16][1024];   // 64 KB kr ring
  __shared__ float bigtab[32][16];   // mask table: [j%32][n]
  const int t  = threadIdx.x;
  const int w  = t >> 6, l = t & 63;
  const int b  = blockIdx.x & 3;
  const int i0 = (blockIdx.x >> 2) * 8;

  // mask table (faithful scrambled-mask semantics)
  for (int idx = t; idx < 512; idx += 256) {
    const int jj = idx >> 4, n = idx & 15;
    const int k_ = jj * 64 + b * 16 + n;
    const float m = (k_ < kMem) ? 1.0f : amask[(i0 >> 8) * kS + (k_ - kMem)];
    bigtab[jj][n] = (1.0f - m) * 1e9f;
  }
  // ring preload: rows top0-7 .. top0-1 (always in [0, 1022])
  const int top0 = kS - 1 - i0;
  for (int d = 0; d < 7; ++d) {
    const int r = top0 - 7 + d;
    const float4 val = *(const float4*)(Rm + (size_t)r * kH + 4 * t);
    *(float4*)&ring[r & 15][4 * t] = val;
  }

  const int fb = 4 * l;
  float4 qu[2][4], qv[2][4], acc[2][4];
#pragma unroll
  for (int ii = 0; ii < 2; ++ii) {
    const int i = i0 + 2 * w + ii;
    const float* qrow = Qm + (size_t)(i * 4 + b) * kH;
#pragma unroll
    for (int e = 0; e < 4; ++e) {
      const float4 q4 = *(const float4*)(qrow + fb + 256 * e);
      const float4 u4 = *(const float4*)(u_ + fb + 256 * e);
      const float4 v4 = *(const float4*)(v_ + fb + 256 * e);
      qu[ii][e] = make_float4(q4.x + u4.x, q4.y + u4.y, q4.z + u4.z, q4.w + u4.w);
      qv[ii][e] = make_float4(q4.x + v4.x, q4.y + v4.y, q4.z + v4.z, q4.w + v4.w);
      acc[ii][e] = make_float4(0.f, 0.f, 0.f, 0.f);
    }
  }
  __syncthreads();

  for (int j = 0; j < kK; ++j) {
    {  // stage ring row j+top0 (zeros when out of range => bd contribution 0)
      const int rn = top0 + j;
      float4 val = make_float4(0.f, 0.f, 0.f, 0.f);
      if (rn < kK) val = *(const float4*)(Rm + (size_t)rn * kH + 4 * t);
      *(float4*)&ring[rn & 15][4 * t] = val;
    }
    __syncthreads();  // slot being overwritten next iter is outside all live windows

    const size_t jb = (size_t)(j * 4 + b) * kH;
    float4 kreg[4], vreg[4];
#pragma unroll
    for (int e = 0; e < 4; ++e) kreg[e] = *(const float4*)(Km + jb + fb + 256 * e);
#pragma unroll
    for (int e = 0; e < 4; ++e) vreg[e] = *(const float4*)(Vm + jb + fb + 256 * e);
    float big[4];
#pragma unroll
    for (int e = 0; e < 4; ++e) big[e] = bigtab[j & 31][(l >> 4) + 4 * e];

#pragma unroll
    for (int ii = 0; ii < 2; ++ii) {
      const int i = i0 + 2 * w + ii;
      const int r = j + (kS - 1) - i;
      float p[4];
#pragma unroll
      for (int e = 0; e < 4; ++e)
        p[e] = qu[ii][e].x * kreg[e].x + qu[ii][e].y * kreg[e].y +
               qu[ii][e].z * kreg[e].z + qu[ii][e].w * kreg[e].w;
      if (r < kK) {
        const float* rr = &ring[r & 15][0];
#pragma unroll
        for (int e = 0; e < 4; ++e) {
          const float4 k4 = *(const float4*)(rr + fb + 256 * e);
          p[e] += qv[ii][e].x * k4.x + qv[ii][e].y * k4.y +
                  qv[ii][e].z * k4.z + qv[ii][e].w * k4.w;
        }
      }
      // reduce partials over the 16-lane group (d dimension)
#pragma unroll
      for (int mk = 1; mk <= 8; mk <<= 1) {
#pragma unroll
        for (int e = 0; e < 4; ++e) p[e] += __shfl_xor(p[e], mk);
      }
      float s[4];
#pragma unroll
      for (int e = 0; e < 4; ++e) s[e] = p[e] * 0.125f - big[e];
      // softmax over 16 heads: 4 in-lane + cross-group xor 16/32
      float mx = fmaxf(fmaxf(s[0], s[1]), fmaxf(s[2], s[3]));
      mx = fmaxf(mx, __shfl_xor(mx, 16));
      mx = fmaxf(mx, __shfl_xor(mx, 32));
      float ex[4];
#pragma unroll
      for (int e = 0; e < 4; ++e) ex[e] = __expf(s[e] - mx);
      float sum = ex[0] + ex[1] + ex[2] + ex[3];
      sum += __shfl_xor(sum, 16);
      sum += __shfl_xor(sum, 32);
      const float inv = 1.0f / sum;
#pragma unroll
      for (int e = 0; e < 4; ++e) {
        const float pp = ex[e] * inv;
        acc[ii][e].x += pp * vreg[e].x;
        acc[ii][e].y += pp * vreg[e].y;
        acc[ii][e].z += pp * vreg[e].z;
        acc[ii][e].w += pp * vreg[e].w;
      }
    }
  }
#pragma unroll
  for (int ii = 0; ii < 2; ++ii) {
    const int i = i0 + 2 * w + ii;
    float* orow = OP + (size_t)(i * 4 + b) * kH;
#pragma unroll
    for (int e = 0; e < 4; ++e) *(float4*)(orow + fb + 256 * e) = acc[ii][e];
  }
}

// ---------------------------------------------------------------------------
// mems_new[0,b,t,:] = t < 1024 ? mems[0,b,t,:] : out[b, t-1024, :]
// ---------------------------------------------------------------------------
__global__ __launch_bounds__(256) void mems_kernel(
    const float* __restrict__ mems, const float* __restrict__ out,
    float* __restrict__ dst) {
  const size_t idx = ((size_t)blockIdx.x * 256 + threadIdx.x) * 4;
  const int tt = (int)((idx >> 10) & 2047);
  if (tt < kMem) {
    *(float4*)(dst + idx) = *(const float4*)(mems + idx);
  } else {
    const int bb = (int)(idx >> 21);
    const int h  = (int)(idx & 1023);
    const size_t src = ((size_t)(bb * kS + (tt - kMem))) * kH + h;
    *(float4*)(dst + idx) = *(const float4*)(out + src);
  }
}

}  // namespace

extern "C" void kernel_launch(void* const* d_in, const int* in_sizes, int n_in,
                              void* d_out, int out_size, void* d_ws, size_t ws_size,
                              hipStream_t stream) {
  (void)in_sizes; (void)n_in; (void)out_size; (void)ws_size;
  const float* temb  = (const float*)d_in[0];
  const float* rel   = (const float*)d_in[1];
  const float* mems  = (const float*)d_in[2];
  const float* amask = (const float*)d_in[3];
  const float* Wq = (const float*)d_in[4];
  const float* bq = (const float*)d_in[5];
  const float* Wk = (const float*)d_in[6];
  const float* bk = (const float*)d_in[7];
  const float* Wv = (const float*)d_in[8];
  const float* bv = (const float*)d_in[9];
  const float* Wr = (const float*)d_in[10];
  const float* br = (const float*)d_in[11];
  const float* Wo = (const float*)d_in[12];
  const float* bo = (const float*)d_in[13];
  const float* uu = (const float*)d_in[14];
  const float* vv = (const float*)d_in[15];

  float* out     = (float*)d_out;              // 4096 x 1024
  float* memsOut = out + 4194304;              // 4 x 2048 x 1024
  float* OP      = memsOut;                    // pre-projection attn out (scratch)

  float* Qm = (float*)d_ws;                    // 4096 x 1024
  float* Km = Qm + 4194304;                    // 8192 x 1024
  float* Vm = Km + 8388608;                    // 8192 x 1024
  float* Rm = Vm + 8388608;                    // 2048 x 1024  (total 92.3 MB)

  const dim3 blk(256);
  gemm_bias_kernel<0><<<dim3(32, 16), blk, 0, stream>>>(temb, nullptr, nullptr, Wq, bq, Qm);
  gemm_bias_kernel<1><<<dim3(64, 16), blk, 0, stream>>>(nullptr, temb, mems, Wk, bk, Km);
  gemm_bias_kernel<1><<<dim3(64, 16), blk, 0, stream>>>(nullptr, temb, mems, Wv, bv, Vm);
  gemm_bias_kernel<0><<<dim3(16, 16), blk, 0, stream>>>(rel, nullptr, nullptr, Wr, br, Rm);
  attn_kernel<<<dim3(512), blk, 0, stream>>>(Qm, Km, Vm, Rm, uu, vv, amask, OP);
  gemm_bias_kernel<0><<<dim3(32, 16), blk, 0, stream>>>(OP, nullptr, nullptr, Wo, bo, out);
  mems_kernel<<<dim3(8192), blk, 0, stream>>>(mems, out, memsOut);
}

// Round 4
// 1547.198 us; speedup vs baseline: 2.8602x; 2.8602x over previous
//
#include <hip/hip_runtime.h>
#include <cstdint>
#include <cstddef>

namespace {

constexpr int kS   = 1024;   // query length
constexpr int kH   = 1024;   // hidden
constexpr int kMem = 1024;   // MEM_LEN
constexpr int kK   = 2048;   // S + MEM_LEN

typedef float  f32x4  __attribute__((ext_vector_type(4)));
typedef short  s16x4  __attribute__((ext_vector_type(4)));
typedef short  s16x8  __attribute__((ext_vector_type(8)));

__device__ inline unsigned short f2bf(float f) {
  unsigned u = __float_as_uint(f);
  u = (u + 0x7FFFu + ((u >> 16) & 1u)) >> 16;   // RNE
  return (unsigned short)u;
}
__device__ inline float bf2f(unsigned short s) {
  return __uint_as_float(((unsigned)s) << 16);
}

__device__ inline f32x4 mfma32(s16x8 a, s16x8 b, f32x4 c) {
  return __builtin_amdgcn_mfma_f32_16x16x32_bf16(a, b, c, 0, 0, 0);
}
__device__ inline f32x4 mfma16(s16x4 a, s16x4 b, f32x4 c) {
#if __has_builtin(__builtin_amdgcn_mfma_f32_16x16x16bf16_1k)
  return __builtin_amdgcn_mfma_f32_16x16x16bf16_1k(a, b, c, 0, 0, 0);
#else
  f32x4 d;
  asm volatile("v_mfma_f32_16x16x16_bf16 %0, %1, %2, %3"
               : "=v"(d) : "v"(a), "v"(b), "v"(c));
  return d;
#endif
}

// ---------------------------------------------------------------------------
// GEMM: C[M,1024] = A[M,1024] @ W^T + bias.
// IN_MODE  0: rows direct from A;  1: kv_in gather (temb / mems)
// OUT_MODE 0: f32 row-major; 1: bf16 row-major; 2: bf16 transposed V
//            (Vt[b][h][j] with b = row&3, j = row>>2, h = col)
// ---------------------------------------------------------------------------
template <int IN_MODE, int OUT_MODE>
__global__ __launch_bounds__(256) void gemm_bias_kernel(
    const float* __restrict__ A, const float* __restrict__ temb,
    const float* __restrict__ mems, const float* __restrict__ W,
    const float* __restrict__ bias, float* __restrict__ Cf,
    unsigned short* __restrict__ Cb) {
  __shared__ float As[16][132];
  __shared__ float Bs[16][68];
  const int t  = threadIdx.x;
  const int bm = blockIdx.x;
  const int bn = blockIdx.y;
  const int tm = t & 15, tn = t >> 4;
  const int lr = t >> 1, lk = (t & 1) * 8;
  const int wr = t >> 2, wk = (t & 3) * 4;

  const float* arow;
  {
    const int r = bm * 128 + lr;
    if (IN_MODE == 0) {
      arow = A + (size_t)r * kH;
    } else {
      const int bb = r >> 11, jj = r & 2047;
      arow = (jj < kS) ? (temb + ((size_t)bb * kS + jj) * kH)
                       : (mems + ((size_t)bb * kK + (jj - kS)) * kH);
    }
  }
  const float* wrow = W + (size_t)(bn * 64 + wr) * kH;

  float c[8][4] = {};
  for (int k0 = 0; k0 < kH; k0 += 16) {
    const float4 a0 = *(const float4*)(arow + k0 + lk);
    const float4 a1 = *(const float4*)(arow + k0 + lk + 4);
    const float4 w0 = *(const float4*)(wrow + k0 + wk);
    __syncthreads();
    As[lk + 0][lr] = a0.x; As[lk + 1][lr] = a0.y;
    As[lk + 2][lr] = a0.z; As[lk + 3][lr] = a0.w;
    As[lk + 4][lr] = a1.x; As[lk + 5][lr] = a1.y;
    As[lk + 6][lr] = a1.z; As[lk + 7][lr] = a1.w;
    Bs[wk + 0][wr] = w0.x; Bs[wk + 1][wr] = w0.y;
    Bs[wk + 2][wr] = w0.z; Bs[wk + 3][wr] = w0.w;
    __syncthreads();
#pragma unroll
    for (int k = 0; k < 16; ++k) {
      const float4 av0 = *(const float4*)&As[k][tm * 8];
      const float4 av1 = *(const float4*)&As[k][tm * 8 + 4];
      const float4 bv  = *(const float4*)&Bs[k][tn * 4];
      const float am[8] = {av0.x, av0.y, av0.z, av0.w, av1.x, av1.y, av1.z, av1.w};
      const float bb[4] = {bv.x, bv.y, bv.z, bv.w};
#pragma unroll
      for (int mi = 0; mi < 8; ++mi)
#pragma unroll
        for (int ni = 0; ni < 4; ++ni) c[mi][ni] += am[mi] * bb[ni];
    }
  }
  const float4 bi = *(const float4*)(bias + bn * 64 + tn * 4);
  const float bia[4] = {bi.x, bi.y, bi.z, bi.w};
#pragma unroll
  for (int mi = 0; mi < 8; ++mi) {
    const int row = bm * 128 + tm * 8 + mi;
    const int col = bn * 64 + tn * 4;
    if (OUT_MODE == 0) {
      const float4 o = make_float4(c[mi][0] + bia[0], c[mi][1] + bia[1],
                                   c[mi][2] + bia[2], c[mi][3] + bia[3]);
      *(float4*)(Cf + (size_t)row * kH + col) = o;
    } else if (OUT_MODE == 1) {
      s16x4 o;
#pragma unroll
      for (int ni = 0; ni < 4; ++ni) o[ni] = (short)f2bf(c[mi][ni] + bia[ni]);
      *(s16x4*)(Cb + (size_t)row * kH + col) = o;
    } else {
#pragma unroll
      for (int ni = 0; ni < 4; ++ni) {
        Cb[((size_t)(row & 3) * kH + col + ni) * kK + (row >> 2)] =
            f2bf(c[mi][ni] + bia[ni]);
      }
    }
  }
}

// ---------------------------------------------------------------------------
// U[r,n] = u[n]·Kb[r, n*64..], r in [0,8192);  Vp[r,n] = v[n]·Rb[r, n*64..]
// ---------------------------------------------------------------------------
__global__ __launch_bounds__(256) void uvp_kernel(
    const unsigned short* __restrict__ Kb, const unsigned short* __restrict__ Rb,
    const float* __restrict__ u_, const float* __restrict__ v_,
    float* __restrict__ U, float* __restrict__ Vp) {
  int tid = blockIdx.x * 256 + threadIdx.x;
  if (tid < 131072) {
    const int r = tid >> 4, n = tid & 15;
    const unsigned short* p = Kb + (size_t)r * kH + n * 64;
    const float* uu = u_ + n * 64;
    float s = 0.f;
#pragma unroll
    for (int d0 = 0; d0 < 64; d0 += 8) {
      s16x8 kv = *(const s16x8*)(p + d0);
#pragma unroll
      for (int e = 0; e < 8; ++e) s += bf2f((unsigned short)kv[e]) * uu[d0 + e];
    }
    U[tid] = s;
  } else {
    tid -= 131072;
    if (tid < 32768) {
      const int r = tid >> 4, n = tid & 15;
      const unsigned short* p = Rb + (size_t)r * kH + n * 64;
      const float* vv = v_ + n * 64;
      float s = 0.f;
#pragma unroll
      for (int d0 = 0; d0 < 64; d0 += 8) {
        s16x8 kv = *(const s16x8*)(p + d0);
#pragma unroll
        for (int e = 0; e < 8; ++e) s += bf2f((unsigned short)kv[e]) * vv[d0 + e];
      }
      Vp[tid] = s;
    }
  }
}

__global__ __launch_bounds__(256) void zero_kernel(float* __restrict__ p) {
  const size_t idx = ((size_t)blockIdx.x * 256 + threadIdx.x) * 4;
  *(float4*)(p + idx) = make_float4(0.f, 0.f, 0.f, 0.f);
}

// ---------------------------------------------------------------------------
// MFMA attention. Block = (b, i-tile of 16, j-half). 4 waves; wave w owns
// heads 4w..4w+3 for all 16 i's. Swapped MFMA: S^T[j][i] so per-(i,j) head
// values are lane-local across accumulators; softmax over heads via a 4-wave
// LDS combine (2 barriers/step). rel-shift bd term via rolling D band (3x16
// r-cols in LDS, col = r mod 48), produced by MFMA each step. PV uses the
// P^T C-frag directly as the B-operand of mfma 16x16x16 (layout identity),
// with V^T A-frags loaded straight from the transposed Vt buffer.
// ---------------------------------------------------------------------------
__global__ __launch_bounds__(256) void attn_mfma_kernel(
    const unsigned short* __restrict__ Qb, const unsigned short* __restrict__ Kb,
    const unsigned short* __restrict__ Rb, const unsigned short* __restrict__ Vt,
    const float* __restrict__ Ug, const float* __restrict__ Vpg,
    const float* __restrict__ amask, float* __restrict__ OP) {
  __shared__ unsigned short Dl[4][4][16][50];  // [wave][head][i][rcol(48)+pad]
  __shared__ float smA[4][16][16];             // per-wave partial max  [j][i]
  __shared__ float smB[4][16][16];             // per-wave partial sum  [j][i]
  __shared__ float bigtab[32][16];

  const int t  = threadIdx.x;
  const int w  = t >> 6, l = t & 63;
  const int li = l & 15;         // i-local (and A-row local)
  const int lg = l >> 4;         // lane group
  const int b   = blockIdx.x & 3;
  const int i0  = ((blockIdx.x >> 2) & 63) * 16;
  const int jh  = blockIdx.x >> 8;
  const int js0 = jh * 1024;
  const int n0  = w * 4;

  // mask table (faithful scrambled-mask semantics; selector row = i>>8)
  for (int idx = t; idx < 512; idx += 256) {
    const int jj = idx >> 4, n = idx & 15;
    const int k_ = jj * 64 + b * 16 + n;
    const float m = (k_ < kMem) ? 1.0f : amask[(i0 >> 8) * kS + (k_ - kMem)];
    bigtab[jj][n] = (1.0f - m) * 1e9f;
  }

  // Q B-frags for this wave's 4 heads (resident whole kernel)
  s16x8 qf[4][2];
#pragma unroll
  for (int h = 0; h < 4; ++h)
#pragma unroll
    for (int ks = 0; ks < 2; ++ks)
      qf[h][ks] = *(const s16x8*)(Qb + ((size_t)(i0 + li) * 4 + b) * kH +
                                  (n0 + h) * 64 + ks * 32 + lg * 8);

  f32x4 out[4][4];
#pragma unroll
  for (int h = 0; h < 4; ++h)
#pragma unroll
    for (int d = 0; d < 4; ++d) out[h][d] = f32x4{0.f, 0.f, 0.f, 0.f};

  // rolling-band D producer: D[i][r] = q_i . kr_r (+ Vp), r-tile at rbase.
  // rbase may be negative (prologue) or exceed kK (tail): reads clamped,
  // stores guarded / positive-mod; garbage columns are overwritten in-wave
  // before any read of them.
  auto d_produce = [&](int rbase) {
    const int rowc = max(0, min(rbase + li, kK - 1));
    const int colb = ((rbase % 48) + 48) % 48 + lg * 4;
#pragma unroll
    for (int h = 0; h < 4; ++h) {
      f32x4 dacc = f32x4{0.f, 0.f, 0.f, 0.f};
#pragma unroll
      for (int ks = 0; ks < 2; ++ks) {
        s16x8 af = *(const s16x8*)(Rb + (size_t)rowc * kH +
                                   (n0 + h) * 64 + ks * 32 + lg * 8);
        dacc = mfma32(af, qf[h][ks], dacc);
      }
#pragma unroll
      for (int reg = 0; reg < 4; ++reg) {
        const int r = rbase + lg * 4 + reg;
        float val = 0.f;
        if (r >= 0 && r < kK) val = dacc[reg] + Vpg[r * 16 + n0 + h];
        Dl[w][h][li][colb + reg] = f2bf(val);
      }
    }
  };

  __syncthreads();  // bigtab ready

  // prologue: two band tiles
  d_produce(js0 - i0 + 992);
  d_produce(js0 - i0 + 1008);

  for (int js = js0; js < js0 + 1024; js += 16) {
    d_produce(js - i0 + 1024);  // newest band tile

    // ac: S^T = K x Q per head
    f32x4 s[4];
#pragma unroll
    for (int h = 0; h < 4; ++h) {
      f32x4 sc = f32x4{0.f, 0.f, 0.f, 0.f};
#pragma unroll
      for (int ks = 0; ks < 2; ++ks) {
        s16x8 kf = *(const s16x8*)(Kb + ((size_t)(js + li) * 4 + b) * kH +
                                   (n0 + h) * 64 + ks * 32 + lg * 8);
        sc = mfma32(kf, qf[h][ks], sc);
      }
      s[h] = sc;
    }
    // assemble scores: element (lane,reg) = (i = i0+li, j = js + lg*4+reg)
#pragma unroll
    for (int h = 0; h < 4; ++h) {
#pragma unroll
      for (int reg = 0; reg < 4; ++reg) {
        const int jl = lg * 4 + reg;
        const int j  = js + jl;
        const int r  = j + (kS - 1) - (i0 + li);
        const float sbd = bf2f(Dl[w][h][li][r % 48]);
        const float uu  = Ug[((size_t)j * 4 + b) * 16 + n0 + h];
        s[h][reg] = (s[h][reg] + sbd + uu) * 0.125f - bigtab[j & 31][n0 + h];
      }
    }
    // cross-wave softmax over 16 heads
#pragma unroll
    for (int reg = 0; reg < 4; ++reg) {
      float m4 = fmaxf(fmaxf(s[0][reg], s[1][reg]), fmaxf(s[2][reg], s[3][reg]));
      smA[w][lg * 4 + reg][li] = m4;
    }
    __syncthreads();
    float M[4], ex[4][4], inv[4];
#pragma unroll
    for (int reg = 0; reg < 4; ++reg) {
      const int jl = lg * 4 + reg;
      M[reg] = fmaxf(fmaxf(smA[0][jl][li], smA[1][jl][li]),
                     fmaxf(smA[2][jl][li], smA[3][jl][li]));
      float sm = 0.f;
#pragma unroll
      for (int h = 0; h < 4; ++h) { ex[h][reg] = __expf(s[h][reg] - M[reg]); sm += ex[h][reg]; }
      smB[w][jl][li] = sm;
    }
    __syncthreads();
#pragma unroll
    for (int reg = 0; reg < 4; ++reg) {
      const int jl = lg * 4 + reg;
      const float L = smB[0][jl][li] + smB[1][jl][li] + smB[2][jl][li] + smB[3][jl][li];
      inv[reg] = 1.0f / L;
    }
    // PV: out^T[d][i] += V^T x P  (P^T C-frag == B-operand layout, K=16)
#pragma unroll
    for (int h = 0; h < 4; ++h) {
      s16x4 pf;
#pragma unroll
      for (int reg = 0; reg < 4; ++reg) pf[reg] = (short)f2bf(ex[h][reg] * inv[reg]);
#pragma unroll
      for (int db = 0; db < 4; ++db) {
        s16x4 vf = *(const s16x4*)(Vt + ((size_t)b * kH + (n0 + h) * 64 +
                                         db * 16 + li) * kK + js + lg * 4);
        out[h][db] = mfma16(vf, pf, out[h][db]);
      }
    }
  }

  // epilogue: atomic accumulate (j-halves sum into OP)
#pragma unroll
  for (int h = 0; h < 4; ++h)
#pragma unroll
    for (int db = 0; db < 4; ++db) {
      const size_t base = ((size_t)(i0 + li) * 4 + b) * kH +
                          (n0 + h) * 64 + db * 16 + lg * 4;
#pragma unroll
      for (int reg = 0; reg < 4; ++reg) atomicAdd(&OP[base + reg], out[h][db][reg]);
    }
}

// ---------------------------------------------------------------------------
// mems_new[0,b,t,:] = t < 1024 ? mems[0,b,t,:] : out[b, t-1024, :]
// ---------------------------------------------------------------------------
__global__ __launch_bounds__(256) void mems_kernel(
    const float* __restrict__ mems, const float* __restrict__ out,
    float* __restrict__ dst) {
  const size_t idx = ((size_t)blockIdx.x * 256 + threadIdx.x) * 4;
  const int tt = (int)((idx >> 10) & 2047);
  if (tt < kMem) {
    *(float4*)(dst + idx) = *(const float4*)(mems + idx);
  } else {
    const int bb = (int)(idx >> 21);
    const int h  = (int)(idx & 1023);
    const size_t src = ((size_t)(bb * kS + (tt - kMem))) * kH + h;
    *(float4*)(dst + idx) = *(const float4*)(out + src);
  }
}

}  // namespace

extern "C" void kernel_launch(void* const* d_in, const int* in_sizes, int n_in,
                              void* d_out, int out_size, void* d_ws, size_t ws_size,
                              hipStream_t stream) {
  (void)in_sizes; (void)n_in; (void)out_size; (void)ws_size;
  const float* temb  = (const float*)d_in[0];
  const float* rel   = (const float*)d_in[1];
  const float* mems  = (const float*)d_in[2];
  const float* amask = (const float*)d_in[3];
  const float* Wq = (const float*)d_in[4];
  const float* bq = (const float*)d_in[5];
  const float* Wk = (const float*)d_in[6];
  const float* bk = (const float*)d_in[7];
  const float* Wv = (const float*)d_in[8];
  const float* bv = (const float*)d_in[9];
  const float* Wr = (const float*)d_in[10];
  const float* br = (const float*)d_in[11];
  const float* Wo = (const float*)d_in[12];
  const float* bo = (const float*)d_in[13];
  const float* uu = (const float*)d_in[14];
  const float* vv = (const float*)d_in[15];

  float* out     = (float*)d_out;             // 4096 x 1024
  float* memsOut = out + 4194304;             // 4 x 2048 x 1024

  char* ws = (char*)d_ws;
  unsigned short* Qb = (unsigned short*)(ws);                 // 4096x1024 bf16
  unsigned short* Kb = (unsigned short*)(ws + 8388608);       // 8192x1024 bf16
  unsigned short* Rb = (unsigned short*)(ws + 25165824);      // 2048x1024 bf16
  unsigned short* Vt = (unsigned short*)(ws + 29360128);      // 4x1024x2048 bf16
  float*          OP = (float*)(ws + 46137344);               // 4096x1024 f32
  float*          Ug = (float*)(ws + 62914560);               // 8192x16 f32
  float*          Vp = (float*)(ws + 63438848);               // 2048x16 f32

  const dim3 blk(256);
  gemm_bias_kernel<0, 1><<<dim3(32, 16), blk, 0, stream>>>(temb, nullptr, nullptr, Wq, bq, nullptr, Qb);
  gemm_bias_kernel<1, 1><<<dim3(64, 16), blk, 0, stream>>>(nullptr, temb, mems, Wk, bk, nullptr, Kb);
  gemm_bias_kernel<1, 2><<<dim3(64, 16), blk, 0, stream>>>(nullptr, temb, mems, Wv, bv, nullptr, Vt);
  gemm_bias_kernel<0, 1><<<dim3(16, 16), blk, 0, stream>>>(rel, nullptr, nullptr, Wr, br, nullptr, Rb);
  uvp_kernel<<<dim3(640), blk, 0, stream>>>(Kb, Rb, uu, vv, Ug, Vp);
  zero_kernel<<<dim3(4096), blk, 0, stream>>>(OP);
  attn_mfma_kernel<<<dim3(512), blk, 0, stream>>>(Qb, Kb, Rb, Vt, Ug, Vp, amask, OP);
  gemm_bias_kernel<0, 0><<<dim3(32, 16), blk, 0, stream>>>(OP, nullptr, nullptr, Wo, bo, out, nullptr);
  mems_kernel<<<dim3(8192), blk, 0, stream>>>(mems, out, memsOut);
}